// Round 15
// baseline (199.232 us; speedup 1.0000x reference)
//
#include <hip/hip_runtime.h>

// UniformBottomUpHTMM: T=64 trees, depth 10 (N1=2047 heap), C=16, M=64,
// G=16. r26: move UNIFORM A-reads off the LDS pipe. r25 = 43.2us; cost
// model (validated by r25's -14%): per-wave LDS instruction count is the
// binding resource (~1000 instr/block x 4 blocks/CU x ~12cy ~= 17us pipe
// time in phase-locked bursts). Of those, ~512 are UNIFORM-address A-row
// reads (leaf L8 4x64, L7 2x64, L6 64, tables 64) -- every lane reads the
// same address, yet each occupies the LDS pipe fully, while the scalar/
// SMEM and vector-mem pipes sit idle (FETCH ~1MB).
// Fix: stage A to d_ws + g*256 (16KB total). The 16 same-g blocks write
// BIT-IDENTICAL values (same deterministic softmax) -> concurrent writes
// benign; each block reads only after its own write + __threadfence +
// __syncthreads (barrier drains vmcnt) -> L2 correct. Uniform A-readers
// (tables, L8/L7/L6 matvec) use the global copy (uniform base+literal
// offsets -> s_load / L1-hit); divergent split-tail A-reads keep LDS sA
// (2-address broadcast is what LDS is good at). Both copies written.
// Predicted: LDS instr ~1000 -> ~490; dur 43 -> ~33-38us.
// Tripwires: WRITE_SIZE >> 100KB (spill) or VGPR>128 => revert.
// Structure: 1024 independent blocks, one (t,g) each; ws use = 16KB.

#define C_DIM 16
#define M_DIM 64
#define G_DIM 16
#define T_TREES 64
#define N1 2047
#define NBLOCKS (T_TREES * G_DIM)   // 1024
#define BTS 20                      // padded row stride (floats) for xv-tables

__device__ __forceinline__ float4 f4add(float4 a, float4 b) {
    return make_float4(a.x + b.x, a.y + b.y, a.z + b.z, a.w + b.w);
}
__device__ __forceinline__ float4 f4mul(float4 a, float4 b) {
    return make_float4(a.x * b.x, a.y * b.y, a.z * b.z, a.w * b.w);
}
__device__ __forceinline__ float4 f4fma(float4 a, float4 b, float4 c) {
    return make_float4(fmaf(a.x, b.x, c.x), fmaf(a.y, b.y, c.y),
                       fmaf(a.z, b.z, c.z), fmaf(a.w, b.w, c.w));
}
__device__ __forceinline__ float hsum4(float4 a) { return a.x + a.y + a.z + a.w; }

// bp[q] = (A[4q+r]·s) * Bt[4q+r]; returns nu = sum(bp).
// A pointer is GLOBAL (uniform address -> scalar/L1 path, not LDS).
// Two 8-row halves with a hard sched fence between (r19-proven).
__device__ __forceinline__ float matvec_bt(const float* __restrict__ A,
                                           const float* __restrict__ bt,
                                           const float4 sv[4], float4 bp[4])
{
    float nu = 0.f;
    #pragma unroll
    for (int h = 0; h < 2; ++h) {
        #pragma unroll
        for (int q = 2 * h; q < 2 * h + 2; ++q) {
            const float4 b4 = *(const float4*)(bt + 4 * q);
            float tr[4];
            #pragma unroll
            for (int r = 0; r < 4; ++r) {
                const float4* ar = (const float4*)(A + (4 * q + r) * 16);
                float4 m = f4mul(ar[0], sv[0]);
                m = f4fma(ar[1], sv[1], m);
                m = f4fma(ar[2], sv[2], m);
                m = f4fma(ar[3], sv[3], m);
                tr[r] = hsum4(m);
            }
            bp[q] = f4mul(make_float4(tr[0], tr[1], tr[2], tr[3]), b4);
            nu += hsum4(bp[q]);
        }
        __builtin_amdgcn_sched_barrier(0);   // liveness fence: half-matvec
    }
    return nu;
}

__global__ __launch_bounds__(256, 1) void htmm_fused(
    const int* __restrict__ x,
    const int* __restrict__ inv_map,
    const float* __restrict__ lA,
    const float* __restrict__ lB,
    const float* __restrict__ lPi,
    float* __restrict__ ws,
    float* __restrict__ out)
{
    const int bid = blockIdx.x;           // 1024 blocks: g = bid>>6, t = bid&63
    const int tid = threadIdx.x;
    const int g = bid >> 6;
    const int t = bid & (T_TREES - 1);

    // global copy of A for this g (16 same-g blocks write identical data)
    float* const gA = ws + (size_t)g * 256;

    // ---- manual LDS layout (r21 diet): 32768 B ----
    __shared__ __align__(16) unsigned char smem[32768];
    float* const sA   = (float*)(smem);            //     0 .. 1024   A row-major (split-tail use)
    float* const sBt  = (float*)(smem + 1024);     //  1024 .. 6144   Bt[xv][c] stride 20
    float* const sPB  = (float*)(smem + 6144);     //  6144 .. 11264  tA[x]=A·PB[x] (leaf-phase only)
    float* const sLog = (float*)(smem + 11264);    // 11264 .. 11520  (dead after leaf)
    float* const sPi  = (float*)(smem + 11520);    // 11520 .. 11584  (dead after tables)
    float* const buf1 = (float*)(smem + 6144);     // UNION: live from L7 on (8192B)
    unsigned char* const xs = smem + 14336;        // 14336 .. 16384
    float* const buf0 = (float*)(smem + 16384);    // 16384 .. 32768
    float* const wsum = (float*)(smem + 32752);    // buf0 row15 col252-255 (tail-unused)

    // ---- tree symbols (coalesced; 16 same-tree blocks share L2) ----
    {
        const int base = t * N1;
        for (int i = tid; i < N1; i += 256)
            xs[i] = (unsigned char)x[inv_map[base + i]];
    }
    // ---- A softmax (over i within 16-lane segments): LDS + global copies ----
    {
        int j = tid >> 4, i = tid & 15;
        float v = lA[(i * C_DIM + j) * G_DIM + g];
        float mx = v;
        #pragma unroll
        for (int m = 1; m < 16; m <<= 1) mx = fmaxf(mx, __shfl_xor(mx, m, 16));
        float e = __expf(v - mx);
        float s = e;
        #pragma unroll
        for (int m = 1; m < 16; m <<= 1) s += __shfl_xor(s, m, 16);
        const float av = e / s;
        sA[i * C_DIM + j] = av;
        gA[i * C_DIM + j] = av;    // identical across same-g blocks: benign race
    }
    // ---- B softmax (over m), written TRANSPOSED: sBt[xv*BTS + c] ----
    {
        int c = tid >> 4, l16 = tid & 15;
        float e0 = lB[(c * M_DIM + l16 +  0) * G_DIM + g];
        float e1 = lB[(c * M_DIM + l16 + 16) * G_DIM + g];
        float e2 = lB[(c * M_DIM + l16 + 32) * G_DIM + g];
        float e3 = lB[(c * M_DIM + l16 + 48) * G_DIM + g];
        float mx = fmaxf(fmaxf(e0, e1), fmaxf(e2, e3));
        #pragma unroll
        for (int m = 1; m < 16; m <<= 1) mx = fmaxf(mx, __shfl_xor(mx, m, 16));
        e0 = __expf(e0 - mx); e1 = __expf(e1 - mx);
        e2 = __expf(e2 - mx); e3 = __expf(e3 - mx);
        float s = e0 + e1 + e2 + e3;
        #pragma unroll
        for (int m = 1; m < 16; m <<= 1) s += __shfl_xor(s, m, 16);
        float inv = 1.f / s;
        sBt[(l16 +  0) * BTS + c] = e0 * inv;
        sBt[(l16 + 16) * BTS + c] = e1 * inv;
        sBt[(l16 + 32) * BTS + c] = e2 * inv;
        sBt[(l16 + 48) * BTS + c] = e3 * inv;
    }
    if (tid < C_DIM) {  // Pi softmax
        float v = lPi[tid * G_DIM + g];
        float mx = v;
        #pragma unroll
        for (int m = 1; m < 16; m <<= 1) mx = fmaxf(mx, __shfl_xor(mx, m, 16));
        float e = __expf(v - mx);
        float s = e;
        #pragma unroll
        for (int m = 1; m < 16; m <<= 1) s += __shfl_xor(s, m, 16);
        sPi[tid] = e / s;
    }
    __threadfence();     // gA writes ordered to L2 before any block-mate reads
    __syncthreads();     // (compiler drains vmcnt before s_barrier)

    // ---- leaf tables + LINEARITY fold: write tA[x] = A·PB[x] (A via gA) ----
    if (tid < M_DIM) {
        const int xv = tid;
        float pb[16]; float nu = 0.f;
        #pragma unroll
        for (int k = 0; k < 16; ++k) {
            pb[k] = sPi[k] * sBt[xv * BTS + k];
            nu += pb[k];
        }
        const float inv = 0.5f / nu;
        #pragma unroll
        for (int k = 0; k < 16; ++k) pb[k] *= inv;
        sLog[xv] = __logf(nu);
        const float4 pv0 = make_float4(pb[0],  pb[1],  pb[2],  pb[3]);
        const float4 pv1 = make_float4(pb[4],  pb[5],  pb[6],  pb[7]);
        const float4 pv2 = make_float4(pb[8],  pb[9],  pb[10], pb[11]);
        const float4 pv3 = make_float4(pb[12], pb[13], pb[14], pb[15]);
        float ta[16];
        #pragma unroll
        for (int i = 0; i < 16; ++i) {
            const float4* ar = (const float4*)(gA + i * 16);
            float4 m = f4mul(ar[0], pv0);
            m = f4fma(ar[1], pv1, m);
            m = f4fma(ar[2], pv2, m);
            m = f4fma(ar[3], pv3, m);
            ta[i] = hsum4(m);
            if ((i & 3) == 3) __builtin_amdgcn_sched_barrier(0);  // cap in-flight
        }
        #pragma unroll
        for (int q = 0; q < 4; ++q)
            *(float4*)(&sPB[xv * BTS + 4 * q]) =
                make_float4(ta[4*q], ta[4*q+1], ta[4*q+2], ta[4*q+3]);
    }
    __syncthreads();

    float ll = 0.f;

    // ---- fused leaves+L9 (TABLE, both subtrees interleaved) + L8 ----
    {
        const int idx = tid;
        const int p8  = 255 + idx;
        const int xl0 = xs[4 * p8 + 3], xr0 = xs[4 * p8 + 4];
        const int xl1 = xs[4 * p8 + 5], xr1 = xs[4 * p8 + 6];
        const int xva = xs[2 * p8 + 1], xvb = xs[2 * p8 + 2];
        const int xv8 = xs[p8];

        const float* tl0 = &sPB[xl0 * BTS];
        const float* tr0 = &sPB[xr0 * BTS];
        const float* tl1 = &sPB[xl1 * BTS];
        const float* tr1 = &sPB[xr1 * BTS];
        const float* bta = &sBt[xva * BTS];
        const float* btb = &sBt[xvb * BTS];

        float4 bpa[4], bpb[4];
        float nua = 0.f, nub = 0.f;
        #pragma unroll
        for (int q = 0; q < 4; ++q) {
            float4 tva = f4add(*(const float4*)(tl0 + 4*q),
                               *(const float4*)(tr0 + 4*q));
            float4 tvb = f4add(*(const float4*)(tl1 + 4*q),
                               *(const float4*)(tr1 + 4*q));
            bpa[q] = f4mul(tva, *(const float4*)(bta + 4*q));
            bpb[q] = f4mul(tvb, *(const float4*)(btb + 4*q));
            nua += hsum4(bpa[q]);
            nub += hsum4(bpb[q]);
        }
        const float ia = 0.5f / nua, ib = 0.5f / nub;
        float4 s8v[4];
        #pragma unroll
        for (int q = 0; q < 4; ++q)
            s8v[q] = f4add(f4mul(bpa[q], make_float4(ia, ia, ia, ia)),
                           f4mul(bpb[q], make_float4(ib, ib, ib, ib)));

        float4 bp[4];
        const float nu8 = matvec_bt(gA, &sBt[xv8 * BTS], s8v, bp);
        ll += sLog[xl0] + sLog[xr0] + sLog[xl1] + sLog[xr1]
            + __logf(nua * nub * nu8);
        const float inv = 1.f / nu8;
        #pragma unroll
        for (int q = 0; q < 4; ++q) {
            buf0[(4*q + 0) * 256 + idx] = bp[q].x * inv;
            buf0[(4*q + 1) * 256 + idx] = bp[q].y * inv;
            buf0[(4*q + 2) * 256 + idx] = bp[q].z * inv;
            buf0[(4*q + 3) * 256 + idx] = bp[q].w * inv;
        }
    }
    __syncthreads();

    // ---- L7: 128 nodes (buf1 aliases the now-dead tA region) ----
    if (tid < 128) {
        const int idx = tid;
        float4 sv[4];
        #pragma unroll
        for (int q = 0; q < 4; ++q) {
            float2 c0 = *(const float2*)(&buf0[(4*q + 0) * 256 + 2 * idx]);
            float2 c1 = *(const float2*)(&buf0[(4*q + 1) * 256 + 2 * idx]);
            float2 c2 = *(const float2*)(&buf0[(4*q + 2) * 256 + 2 * idx]);
            float2 c3 = *(const float2*)(&buf0[(4*q + 3) * 256 + 2 * idx]);
            sv[q] = make_float4(0.5f * (c0.x + c0.y), 0.5f * (c1.x + c1.y),
                                0.5f * (c2.x + c2.y), 0.5f * (c3.x + c3.y));
        }
        const int xv = xs[127 + idx];
        float4 bp[4];
        float nu = matvec_bt(gA, &sBt[xv * BTS], sv, bp);
        ll += __logf(nu);
        const float inv = 1.f / nu;
        #pragma unroll
        for (int q = 0; q < 4; ++q) {
            buf1[(4*q + 0) * 128 + idx] = bp[q].x * inv;
            buf1[(4*q + 1) * 128 + idx] = bp[q].y * inv;
            buf1[(4*q + 2) * 128 + idx] = bp[q].z * inv;
            buf1[(4*q + 3) * 128 + idx] = bp[q].w * inv;
        }
    }
    __syncthreads();

    // ---- tail: wave 0 only ----
    if (tid < 64) {
        float* cur = buf1; int cs = 128;
        float* nxt = buf0; int ns = 256;

        // L6 (cnt2=64): full-width, all 64 lanes; uniform A via gA
        {
            const int idx = tid;
            float4 sv[4];
            #pragma unroll
            for (int q = 0; q < 4; ++q) {
                float2 c0 = *(const float2*)(&cur[(4*q + 0) * cs + 2 * idx]);
                float2 c1 = *(const float2*)(&cur[(4*q + 1) * cs + 2 * idx]);
                float2 c2 = *(const float2*)(&cur[(4*q + 2) * cs + 2 * idx]);
                float2 c3 = *(const float2*)(&cur[(4*q + 3) * cs + 2 * idx]);
                sv[q] = make_float4(0.5f * (c0.x + c0.y), 0.5f * (c1.x + c1.y),
                                    0.5f * (c2.x + c2.y), 0.5f * (c3.x + c3.y));
            }
            const int xv = xs[63 + idx];
            float4 bp[4];
            float nu = matvec_bt(gA, &sBt[xv * BTS], sv, bp);
            ll += __logf(nu);
            const float inv = 1.f / nu;
            #pragma unroll
            for (int q = 0; q < 4; ++q) {
                nxt[(4*q + 0) * ns + idx] = bp[q].x * inv;
                nxt[(4*q + 1) * ns + idx] = bp[q].y * inv;
                nxt[(4*q + 2) * ns + idx] = bp[q].z * inv;
                nxt[(4*q + 3) * ns + idx] = bp[q].w * inv;
            }
            asm volatile("s_waitcnt lgkmcnt(0)" ::: "memory");
            __builtin_amdgcn_wave_barrier();
            float* tp = cur; cur = nxt; nxt = tp;
            int ts = cs; cs = ns; ns = ts;
        }

        // L5..L0 (cnt2=32..1): hi/lo row-split; DIVERGENT A-reads stay on
        // LDS sA (2-address broadcast, free). nu bit-matches original.
        for (int cnt2 = 32; cnt2 >= 1; cnt2 >>= 1) {
            const int half = tid >> 5;        // 0: rows 0-7, 1: rows 8-15
            const int n    = tid & 31;        // node index
            if (n < cnt2) {
                float4 sv[4];
                #pragma unroll
                for (int q = 0; q < 4; ++q) {
                    float2 c0 = *(const float2*)(&cur[(4*q + 0) * cs + 2 * n]);
                    float2 c1 = *(const float2*)(&cur[(4*q + 1) * cs + 2 * n]);
                    float2 c2 = *(const float2*)(&cur[(4*q + 2) * cs + 2 * n]);
                    float2 c3 = *(const float2*)(&cur[(4*q + 3) * cs + 2 * n]);
                    sv[q] = make_float4(0.5f * (c0.x + c0.y), 0.5f * (c1.x + c1.y),
                                        0.5f * (c2.x + c2.y), 0.5f * (c3.x + c3.y));
                }
                const int xv = xs[cnt2 - 1 + n];
                const float* bt = &sBt[xv * BTS];
                const int r0 = half * 8;      // my first row

                float4 bpA; float hA;         // rows r0..r0+3
                {
                    float tr[4];
                    #pragma unroll
                    for (int r = 0; r < 4; ++r) {
                        const float4* ar = (const float4*)(sA + (r0 + r) * 16);
                        float4 m = f4mul(ar[0], sv[0]);
                        m = f4fma(ar[1], sv[1], m);
                        m = f4fma(ar[2], sv[2], m);
                        m = f4fma(ar[3], sv[3], m);
                        tr[r] = hsum4(m);
                    }
                    bpA = f4mul(make_float4(tr[0], tr[1], tr[2], tr[3]),
                                *(const float4*)(bt + r0));
                    hA = hsum4(bpA);
                }
                __builtin_amdgcn_sched_barrier(0);
                float4 bpB; float hB;         // rows r0+4..r0+7
                {
                    float tr[4];
                    #pragma unroll
                    for (int r = 0; r < 4; ++r) {
                        const float4* ar = (const float4*)(sA + (r0 + 4 + r) * 16);
                        float4 m = f4mul(ar[0], sv[0]);
                        m = f4fma(ar[1], sv[1], m);
                        m = f4fma(ar[2], sv[2], m);
                        m = f4fma(ar[3], sv[3], m);
                        tr[r] = hsum4(m);
                    }
                    bpB = f4mul(make_float4(tr[0], tr[1], tr[2], tr[3]),
                                *(const float4*)(bt + r0 + 4));
                    hB = hsum4(bpB);
                }
                __builtin_amdgcn_sched_barrier(0);

                const float pA = __shfl_xor(hA, 32, 64);  // partner h-pair
                const float pB = __shfl_xor(hB, 32, 64);
                // lo holds (h0,h1), hi holds (h2,h3); both form ((h0+h1)+h2)+h3
                const float nu = half ? (((pA + pB) + hA) + hB)
                                      : (((hA + hB) + pA) + pB);
                if (half == 0) ll += __logf(nu);          // count once
                const float inv = 1.f / nu;
                nxt[(r0 + 0) * ns + n] = bpA.x * inv;
                nxt[(r0 + 1) * ns + n] = bpA.y * inv;
                nxt[(r0 + 2) * ns + n] = bpA.z * inv;
                nxt[(r0 + 3) * ns + n] = bpA.w * inv;
                nxt[(r0 + 4) * ns + n] = bpB.x * inv;
                nxt[(r0 + 5) * ns + n] = bpB.y * inv;
                nxt[(r0 + 6) * ns + n] = bpB.z * inv;
                nxt[(r0 + 7) * ns + n] = bpB.w * inv;
            }
            asm volatile("s_waitcnt lgkmcnt(0)" ::: "memory");
            __builtin_amdgcn_wave_barrier();
            float* tp = cur; cur = nxt; nxt = tp;
            int ts = cs; cs = ns; ns = ts;
        }
    }

    // ---- reduce ll across block (wsum in buf0 row15 cols252-255) ----
    float v = ll;
    #pragma unroll
    for (int off = 32; off > 0; off >>= 1) v += __shfl_down(v, off, 64);
    if ((tid & 63) == 0) wsum[tid >> 6] = v;
    __syncthreads();
    if (tid == 0) out[t * G_DIM + g] = wsum[0] + wsum[1] + wsum[2] + wsum[3];
}

extern "C" void kernel_launch(void* const* d_in, const int* in_sizes, int n_in,
                              void* d_out, int out_size, void* d_ws, size_t ws_size,
                              hipStream_t stream) {
    const int*   x       = (const int*)d_in[0];
    const int*   inv_map = (const int*)d_in[6];
    const float* lA      = (const float*)d_in[7];
    const float* lB      = (const float*)d_in[8];
    const float* lPi     = (const float*)d_in[9];
    float* ws  = (float*)d_ws;
    float* out = (float*)d_out;

    htmm_fused<<<dim3(NBLOCKS), dim3(256), 0, stream>>>(
        x, inv_map, lA, lB, lPi, ws, out);
}

// Round 16
// 108.890 us; speedup vs baseline: 1.8297x; 1.8297x over previous
//
#include <hip/hip_runtime.h>

// UniformBottomUpHTMM: T=64 trees, depth 10 (N1=2047 heap), C=16, M=64,
// G=16. r27: REVERT r26 + leaf lane-pair split.
// r26 post-mortem: global-A staging made matvecs global-latency-bound
// (~200cy/load, no scalarization, fences block overlap) -> 133us,
// VALUBusy 7.9%. Uniform LDS reads were never the latency problem --
// only the ISSUE count. Full revert to r25 (43.2us champion).
// New (leaf only): pair adjacent lanes (idx, idx^1). Each lane computes
// one 8-row half of BOTH nodes' L8 matvecs: A-row reads shared -> 32
// two-address conflict-free instrs/wave (was 64 uniform); total FMA
// unchanged. sv exchanged via __shfl_xor(.,1) (DPP quad-perm, VALU pipe,
// 16 ops) + 4 partial exchanges; nu re-associated to bit-match
// ((h0+h1)+h2)+h3 (r25-tail-proven). L7/L6 NOT paired: their sv comes
// from LDS child reads which would double (r22 lesson: don't add issue
// streams). Saves 128 LDS instr/block (~16%).
// Tripwires: VGPR>128 or WRITE_SIZE>>4KB => revert pairing.
// Structure: 1024 independent blocks, one (t,g) each, no workspace/atomics.

#define C_DIM 16
#define M_DIM 64
#define G_DIM 16
#define T_TREES 64
#define N1 2047
#define NBLOCKS (T_TREES * G_DIM)   // 1024
#define BTS 20                      // padded row stride (floats) for xv-tables

__device__ __forceinline__ float4 f4add(float4 a, float4 b) {
    return make_float4(a.x + b.x, a.y + b.y, a.z + b.z, a.w + b.w);
}
__device__ __forceinline__ float4 f4mul(float4 a, float4 b) {
    return make_float4(a.x * b.x, a.y * b.y, a.z * b.z, a.w * b.w);
}
__device__ __forceinline__ float4 f4fma(float4 a, float4 b, float4 c) {
    return make_float4(fmaf(a.x, b.x, c.x), fmaf(a.y, b.y, c.y),
                       fmaf(a.z, b.z, c.z), fmaf(a.w, b.w, c.w));
}
__device__ __forceinline__ float hsum4(float4 a) { return a.x + a.y + a.z + a.w; }
__device__ __forceinline__ float4 f4shflx1(float4 v) {
    return make_float4(__shfl_xor(v.x, 1, 64), __shfl_xor(v.y, 1, 64),
                       __shfl_xor(v.z, 1, 64), __shfl_xor(v.w, 1, 64));
}

// bp[q] = (A[4q+r]·s) * Bt[4q+r]; returns nu = sum(bp).
// Two 8-row halves with a hard sched fence between (r19-proven).
// A = LDS (uniform broadcast). Used by L7/L6.
__device__ __forceinline__ float matvec_bt(const float* __restrict__ A,
                                           const float* __restrict__ bt,
                                           const float4 sv[4], float4 bp[4])
{
    float nu = 0.f;
    #pragma unroll
    for (int h = 0; h < 2; ++h) {
        #pragma unroll
        for (int q = 2 * h; q < 2 * h + 2; ++q) {
            const float4 b4 = *(const float4*)(bt + 4 * q);
            float tr[4];
            #pragma unroll
            for (int r = 0; r < 4; ++r) {
                const float4* ar = (const float4*)(A + (4 * q + r) * 16);
                float4 m = f4mul(ar[0], sv[0]);
                m = f4fma(ar[1], sv[1], m);
                m = f4fma(ar[2], sv[2], m);
                m = f4fma(ar[3], sv[3], m);
                tr[r] = hsum4(m);
            }
            bp[q] = f4mul(make_float4(tr[0], tr[1], tr[2], tr[3]), b4);
            nu += hsum4(bp[q]);
        }
        __builtin_amdgcn_sched_barrier(0);   // liveness fence: half-matvec
    }
    return nu;
}

__global__ __launch_bounds__(256, 1) void htmm_fused(
    const int* __restrict__ x,
    const int* __restrict__ inv_map,
    const float* __restrict__ lA,
    const float* __restrict__ lB,
    const float* __restrict__ lPi,
    float* __restrict__ out)
{
    const int bid = blockIdx.x;           // 1024 blocks: g = bid>>6, t = bid&63
    const int tid = threadIdx.x;
    const int g = bid >> 6;
    const int t = bid & (T_TREES - 1);

    // ---- manual LDS layout (r21 diet): 32768 B ----
    __shared__ __align__(16) unsigned char smem[32768];
    float* const sA   = (float*)(smem);            //     0 .. 1024   A row-major
    float* const sBt  = (float*)(smem + 1024);     //  1024 .. 6144   Bt[xv][c] stride 20
    float* const sPB  = (float*)(smem + 6144);     //  6144 .. 11264  tA[x]=A·PB[x] (leaf-phase only)
    float* const sLog = (float*)(smem + 11264);    // 11264 .. 11520  (dead after leaf)
    float* const sPi  = (float*)(smem + 11520);    // 11520 .. 11584  (dead after tables)
    float* const buf1 = (float*)(smem + 6144);     // UNION: live from L7 on (8192B)
    unsigned char* const xs = smem + 14336;        // 14336 .. 16384
    float* const buf0 = (float*)(smem + 16384);    // 16384 .. 32768
    float* const wsum = (float*)(smem + 32752);    // buf0 row15 col252-255 (tail-unused)

    // ---- tree symbols (coalesced; 16 same-tree blocks share L2) ----
    {
        const int base = t * N1;
        for (int i = tid; i < N1; i += 256)
            xs[i] = (unsigned char)x[inv_map[base + i]];
    }
    // ---- A softmax (over i within 16-lane segments) ----
    {
        int j = tid >> 4, i = tid & 15;
        float v = lA[(i * C_DIM + j) * G_DIM + g];
        float mx = v;
        #pragma unroll
        for (int m = 1; m < 16; m <<= 1) mx = fmaxf(mx, __shfl_xor(mx, m, 16));
        float e = __expf(v - mx);
        float s = e;
        #pragma unroll
        for (int m = 1; m < 16; m <<= 1) s += __shfl_xor(s, m, 16);
        sA[i * C_DIM + j] = e / s;
    }
    // ---- B softmax (over m), written TRANSPOSED: sBt[xv*BTS + c] ----
    {
        int c = tid >> 4, l16 = tid & 15;
        float e0 = lB[(c * M_DIM + l16 +  0) * G_DIM + g];
        float e1 = lB[(c * M_DIM + l16 + 16) * G_DIM + g];
        float e2 = lB[(c * M_DIM + l16 + 32) * G_DIM + g];
        float e3 = lB[(c * M_DIM + l16 + 48) * G_DIM + g];
        float mx = fmaxf(fmaxf(e0, e1), fmaxf(e2, e3));
        #pragma unroll
        for (int m = 1; m < 16; m <<= 1) mx = fmaxf(mx, __shfl_xor(mx, m, 16));
        e0 = __expf(e0 - mx); e1 = __expf(e1 - mx);
        e2 = __expf(e2 - mx); e3 = __expf(e3 - mx);
        float s = e0 + e1 + e2 + e3;
        #pragma unroll
        for (int m = 1; m < 16; m <<= 1) s += __shfl_xor(s, m, 16);
        float inv = 1.f / s;
        sBt[(l16 +  0) * BTS + c] = e0 * inv;
        sBt[(l16 + 16) * BTS + c] = e1 * inv;
        sBt[(l16 + 32) * BTS + c] = e2 * inv;
        sBt[(l16 + 48) * BTS + c] = e3 * inv;
    }
    if (tid < C_DIM) {  // Pi softmax
        float v = lPi[tid * G_DIM + g];
        float mx = v;
        #pragma unroll
        for (int m = 1; m < 16; m <<= 1) mx = fmaxf(mx, __shfl_xor(mx, m, 16));
        float e = __expf(v - mx);
        float s = e;
        #pragma unroll
        for (int m = 1; m < 16; m <<= 1) s += __shfl_xor(s, m, 16);
        sPi[tid] = e / s;
    }
    __syncthreads();

    // ---- leaf tables + LINEARITY fold: write tA[x] = A·PB[x] ----
    if (tid < M_DIM) {
        const int xv = tid;
        float pb[16]; float nu = 0.f;
        #pragma unroll
        for (int k = 0; k < 16; ++k) {
            pb[k] = sPi[k] * sBt[xv * BTS + k];
            nu += pb[k];
        }
        const float inv = 0.5f / nu;
        #pragma unroll
        for (int k = 0; k < 16; ++k) pb[k] *= inv;
        sLog[xv] = __logf(nu);
        const float4 pv0 = make_float4(pb[0],  pb[1],  pb[2],  pb[3]);
        const float4 pv1 = make_float4(pb[4],  pb[5],  pb[6],  pb[7]);
        const float4 pv2 = make_float4(pb[8],  pb[9],  pb[10], pb[11]);
        const float4 pv3 = make_float4(pb[12], pb[13], pb[14], pb[15]);
        float ta[16];
        #pragma unroll
        for (int i = 0; i < 16; ++i) {
            const float4* ar = (const float4*)(sA + i * 16);
            float4 m = f4mul(ar[0], pv0);
            m = f4fma(ar[1], pv1, m);
            m = f4fma(ar[2], pv2, m);
            m = f4fma(ar[3], pv3, m);
            ta[i] = hsum4(m);
            if ((i & 3) == 3) __builtin_amdgcn_sched_barrier(0);  // cap in-flight
        }
        #pragma unroll
        for (int q = 0; q < 4; ++q)
            *(float4*)(&sPB[xv * BTS + 4 * q]) =
                make_float4(ta[4*q], ta[4*q+1], ta[4*q+2], ta[4*q+3]);
    }
    __syncthreads();

    float ll = 0.f;

    // ---- fused leaves+L9 (TABLE) + L8 via LANE-PAIR split ----
    {
        const int idx = tid;
        const int p8  = 255 + idx;
        const int xl0 = xs[4 * p8 + 3], xr0 = xs[4 * p8 + 4];
        const int xl1 = xs[4 * p8 + 5], xr1 = xs[4 * p8 + 6];
        const int xva = xs[2 * p8 + 1], xvb = xs[2 * p8 + 2];
        const int xv8 = xs[p8];
        const int xv8P = xs[255 + (idx ^ 1)];   // partner's L8 symbol

        const float* tl0 = &sPB[xl0 * BTS];
        const float* tr0 = &sPB[xr0 * BTS];
        const float* tl1 = &sPB[xl1 * BTS];
        const float* tr1 = &sPB[xr1 * BTS];
        const float* bta = &sBt[xva * BTS];
        const float* btb = &sBt[xvb * BTS];

        float4 bpa[4], bpb[4];
        float nua = 0.f, nub = 0.f;
        #pragma unroll
        for (int q = 0; q < 4; ++q) {
            float4 tva = f4add(*(const float4*)(tl0 + 4*q),
                               *(const float4*)(tr0 + 4*q));
            float4 tvb = f4add(*(const float4*)(tl1 + 4*q),
                               *(const float4*)(tr1 + 4*q));
            bpa[q] = f4mul(tva, *(const float4*)(bta + 4*q));
            bpb[q] = f4mul(tvb, *(const float4*)(btb + 4*q));
            nua += hsum4(bpa[q]);
            nub += hsum4(bpb[q]);
        }
        const float ia = 0.5f / nua, ib = 0.5f / nub;
        float4 s8v[4];
        #pragma unroll
        for (int q = 0; q < 4; ++q)
            s8v[q] = f4add(f4mul(bpa[q], make_float4(ia, ia, ia, ia)),
                           f4mul(bpb[q], make_float4(ib, ib, ib, ib)));

        // ---- paired L8 matvec: lane parity p picks rows; A-reads shared ----
        const int p = idx & 1;                 // 0: rows 0-7, 1: rows 8-15
        float4 svP[4];
        #pragma unroll
        for (int q = 0; q < 4; ++q) svP[q] = f4shflx1(s8v[q]);
        const float* btM = &sBt[xv8 * BTS];
        const float* btP = &sBt[xv8P * BTS];

        float4 bpM[2], bpP[2];
        float hM0, hM1, hP0, hP1;
        #pragma unroll
        for (int qi = 0; qi < 2; ++qi) {
            const int q = 2 * p + qi;
            float trM[4], trP[4];
            #pragma unroll
            for (int r = 0; r < 4; ++r) {
                const float4* ar = (const float4*)(sA + (4 * q + r) * 16);
                const float4 a0 = ar[0], a1 = ar[1], a2 = ar[2], a3 = ar[3];
                float4 mM = f4mul(a0, s8v[0]);
                mM = f4fma(a1, s8v[1], mM);
                mM = f4fma(a2, s8v[2], mM);
                mM = f4fma(a3, s8v[3], mM);
                trM[r] = hsum4(mM);
                float4 mP = f4mul(a0, svP[0]);
                mP = f4fma(a1, svP[1], mP);
                mP = f4fma(a2, svP[2], mP);
                mP = f4fma(a3, svP[3], mP);
                trP[r] = hsum4(mP);
            }
            bpM[qi] = f4mul(make_float4(trM[0], trM[1], trM[2], trM[3]),
                            *(const float4*)(btM + 4 * q));
            bpP[qi] = f4mul(make_float4(trP[0], trP[1], trP[2], trP[3]),
                            *(const float4*)(btP + 4 * q));
            if (qi == 0) { hM0 = hsum4(bpM[0]); hP0 = hsum4(bpP[0]); }
            else         { hM1 = hsum4(bpM[1]); hP1 = hsum4(bpP[1]); }
            __builtin_amdgcn_sched_barrier(0);   // liveness fence
        }
        // exchange partials; nu bit-matches ((h0+h1)+h2)+h3
        const float phM0 = __shfl_xor(hM0, 1, 64);
        const float phM1 = __shfl_xor(hM1, 1, 64);
        const float phP0 = __shfl_xor(hP0, 1, 64);
        const float phP1 = __shfl_xor(hP1, 1, 64);
        float nuM, nuP;
        if (p == 0) {   // I hold h0,h1 of mine; partner holds h2,h3 of mine
            nuM = ((hM0 + hM1) + phP0) + phP1;
            nuP = ((hP0 + hP1) + phM0) + phM1;
        } else {        // partner holds h0,h1 of mine (as its P)
            nuM = ((phP0 + phP1) + hM0) + hM1;
            nuP = ((phM0 + phM1) + hP0) + hP1;
        }
        // ll: L9 logs per-thread; L8 logs once per pair (even lane)
        if (p == 0)
            ll += sLog[xl0] + sLog[xr0] + sLog[xl1] + sLog[xr1]
                + __logf(nua * nub * nuM * nuP);
        else
            ll += sLog[xl0] + sLog[xr0] + sLog[xl1] + sLog[xr1]
                + __logf(nua * nub);

        const float invM = 1.f / nuM, invP = 1.f / nuP;
        const int colP = idx ^ 1;
        #pragma unroll
        for (int qi = 0; qi < 2; ++qi) {
            const int rb = (2 * p + qi) * 4;
            buf0[(rb + 0) * 256 + idx]  = bpM[qi].x * invM;
            buf0[(rb + 1) * 256 + idx]  = bpM[qi].y * invM;
            buf0[(rb + 2) * 256 + idx]  = bpM[qi].z * invM;
            buf0[(rb + 3) * 256 + idx]  = bpM[qi].w * invM;
            buf0[(rb + 0) * 256 + colP] = bpP[qi].x * invP;
            buf0[(rb + 1) * 256 + colP] = bpP[qi].y * invP;
            buf0[(rb + 2) * 256 + colP] = bpP[qi].z * invP;
            buf0[(rb + 3) * 256 + colP] = bpP[qi].w * invP;
        }
    }
    __syncthreads();

    // ---- L7: 128 nodes (buf1 aliases the now-dead tA region) ----
    if (tid < 128) {
        const int idx = tid;
        float4 sv[4];
        #pragma unroll
        for (int q = 0; q < 4; ++q) {
            float2 c0 = *(const float2*)(&buf0[(4*q + 0) * 256 + 2 * idx]);
            float2 c1 = *(const float2*)(&buf0[(4*q + 1) * 256 + 2 * idx]);
            float2 c2 = *(const float2*)(&buf0[(4*q + 2) * 256 + 2 * idx]);
            float2 c3 = *(const float2*)(&buf0[(4*q + 3) * 256 + 2 * idx]);
            sv[q] = make_float4(0.5f * (c0.x + c0.y), 0.5f * (c1.x + c1.y),
                                0.5f * (c2.x + c2.y), 0.5f * (c3.x + c3.y));
        }
        const int xv = xs[127 + idx];
        float4 bp[4];
        float nu = matvec_bt(sA, &sBt[xv * BTS], sv, bp);
        ll += __logf(nu);
        const float inv = 1.f / nu;
        #pragma unroll
        for (int q = 0; q < 4; ++q) {
            buf1[(4*q + 0) * 128 + idx] = bp[q].x * inv;
            buf1[(4*q + 1) * 128 + idx] = bp[q].y * inv;
            buf1[(4*q + 2) * 128 + idx] = bp[q].z * inv;
            buf1[(4*q + 3) * 128 + idx] = bp[q].w * inv;
        }
    }
    __syncthreads();

    // ---- tail: wave 0 only ----
    if (tid < 64) {
        float* cur = buf1; int cs = 128;
        float* nxt = buf0; int ns = 256;

        // L6 (cnt2=64): full-width, all 64 lanes
        {
            const int idx = tid;
            float4 sv[4];
            #pragma unroll
            for (int q = 0; q < 4; ++q) {
                float2 c0 = *(const float2*)(&cur[(4*q + 0) * cs + 2 * idx]);
                float2 c1 = *(const float2*)(&cur[(4*q + 1) * cs + 2 * idx]);
                float2 c2 = *(const float2*)(&cur[(4*q + 2) * cs + 2 * idx]);
                float2 c3 = *(const float2*)(&cur[(4*q + 3) * cs + 2 * idx]);
                sv[q] = make_float4(0.5f * (c0.x + c0.y), 0.5f * (c1.x + c1.y),
                                    0.5f * (c2.x + c2.y), 0.5f * (c3.x + c3.y));
            }
            const int xv = xs[63 + idx];
            float4 bp[4];
            float nu = matvec_bt(sA, &sBt[xv * BTS], sv, bp);
            ll += __logf(nu);
            const float inv = 1.f / nu;
            #pragma unroll
            for (int q = 0; q < 4; ++q) {
                nxt[(4*q + 0) * ns + idx] = bp[q].x * inv;
                nxt[(4*q + 1) * ns + idx] = bp[q].y * inv;
                nxt[(4*q + 2) * ns + idx] = bp[q].z * inv;
                nxt[(4*q + 3) * ns + idx] = bp[q].w * inv;
            }
            asm volatile("s_waitcnt lgkmcnt(0)" ::: "memory");
            __builtin_amdgcn_wave_barrier();
            float* tp = cur; cur = nxt; nxt = tp;
            int ts = cs; cs = ns; ns = ts;
        }

        // L5..L0 (cnt2=32..1): hi/lo row-split (r25-proven)
        for (int cnt2 = 32; cnt2 >= 1; cnt2 >>= 1) {
            const int half = tid >> 5;        // 0: rows 0-7, 1: rows 8-15
            const int n    = tid & 31;        // node index
            if (n < cnt2) {
                float4 sv[4];
                #pragma unroll
                for (int q = 0; q < 4; ++q) {
                    float2 c0 = *(const float2*)(&cur[(4*q + 0) * cs + 2 * n]);
                    float2 c1 = *(const float2*)(&cur[(4*q + 1) * cs + 2 * n]);
                    float2 c2 = *(const float2*)(&cur[(4*q + 2) * cs + 2 * n]);
                    float2 c3 = *(const float2*)(&cur[(4*q + 3) * cs + 2 * n]);
                    sv[q] = make_float4(0.5f * (c0.x + c0.y), 0.5f * (c1.x + c1.y),
                                        0.5f * (c2.x + c2.y), 0.5f * (c3.x + c3.y));
                }
                const int xv = xs[cnt2 - 1 + n];
                const float* bt = &sBt[xv * BTS];
                const int r0 = half * 8;      // my first row

                float4 bpA; float hA;         // rows r0..r0+3
                {
                    float tr[4];
                    #pragma unroll
                    for (int r = 0; r < 4; ++r) {
                        const float4* ar = (const float4*)(sA + (r0 + r) * 16);
                        float4 m = f4mul(ar[0], sv[0]);
                        m = f4fma(ar[1], sv[1], m);
                        m = f4fma(ar[2], sv[2], m);
                        m = f4fma(ar[3], sv[3], m);
                        tr[r] = hsum4(m);
                    }
                    bpA = f4mul(make_float4(tr[0], tr[1], tr[2], tr[3]),
                                *(const float4*)(bt + r0));
                    hA = hsum4(bpA);
                }
                __builtin_amdgcn_sched_barrier(0);
                float4 bpB; float hB;         // rows r0+4..r0+7
                {
                    float tr[4];
                    #pragma unroll
                    for (int r = 0; r < 4; ++r) {
                        const float4* ar = (const float4*)(sA + (r0 + 4 + r) * 16);
                        float4 m = f4mul(ar[0], sv[0]);
                        m = f4fma(ar[1], sv[1], m);
                        m = f4fma(ar[2], sv[2], m);
                        m = f4fma(ar[3], sv[3], m);
                        tr[r] = hsum4(m);
                    }
                    bpB = f4mul(make_float4(tr[0], tr[1], tr[2], tr[3]),
                                *(const float4*)(bt + r0 + 4));
                    hB = hsum4(bpB);
                }
                __builtin_amdgcn_sched_barrier(0);

                const float pA = __shfl_xor(hA, 32, 64);  // partner h-pair
                const float pB = __shfl_xor(hB, 32, 64);
                const float nu = half ? (((pA + pB) + hA) + hB)
                                      : (((hA + hB) + pA) + pB);
                if (half == 0) ll += __logf(nu);          // count once
                const float inv = 1.f / nu;
                nxt[(r0 + 0) * ns + n] = bpA.x * inv;
                nxt[(r0 + 1) * ns + n] = bpA.y * inv;
                nxt[(r0 + 2) * ns + n] = bpA.z * inv;
                nxt[(r0 + 3) * ns + n] = bpA.w * inv;
                nxt[(r0 + 4) * ns + n] = bpB.x * inv;
                nxt[(r0 + 5) * ns + n] = bpB.y * inv;
                nxt[(r0 + 6) * ns + n] = bpB.z * inv;
                nxt[(r0 + 7) * ns + n] = bpB.w * inv;
            }
            asm volatile("s_waitcnt lgkmcnt(0)" ::: "memory");
            __builtin_amdgcn_wave_barrier();
            float* tp = cur; cur = nxt; nxt = tp;
            int ts = cs; cs = ns; ns = ts;
        }
    }

    // ---- reduce ll across block (wsum in buf0 row15 cols252-255) ----
    float v = ll;
    #pragma unroll
    for (int off = 32; off > 0; off >>= 1) v += __shfl_down(v, off, 64);
    if ((tid & 63) == 0) wsum[tid >> 6] = v;
    __syncthreads();
    if (tid == 0) out[t * G_DIM + g] = wsum[0] + wsum[1] + wsum[2] + wsum[3];
}

extern "C" void kernel_launch(void* const* d_in, const int* in_sizes, int n_in,
                              void* d_out, int out_size, void* d_ws, size_t ws_size,
                              hipStream_t stream) {
    const int*   x       = (const int*)d_in[0];
    const int*   inv_map = (const int*)d_in[6];
    const float* lA      = (const float*)d_in[7];
    const float* lB      = (const float*)d_in[8];
    const float* lPi     = (const float*)d_in[9];
    float* out = (float*)d_out;

    htmm_fused<<<dim3(NBLOCKS), dim3(256), 0, stream>>>(
        x, inv_map, lA, lB, lPi, out);
}

// Round 17
// 95.158 us; speedup vs baseline: 2.0937x; 1.1443x over previous
//
#include <hip/hip_runtime.h>

// UniformBottomUpHTMM: T=64 trees, depth 10 (N1=2047 heap), C=16, M=64,
// G=16. r28: widen the narrow phases, unfence the back half.
// r27 post-mortem: leaf lane-pairing neutral (43.2->43.7) -- 128 saved
// LDS reads traded for shfl + paired stores (bank conflicts 896K->1.44M).
// Leaf reverted to r25 form. Budget: VALU ~9us, LDS-pipe ~12us, rest =
// exposed dependent latency in the NARROW phases (L7 2 waves, L6+tail 1
// wave, every matvec half fenced -> each ~120cy LDS round-trip exposed).
// Fences were r17 medicine (VGPR 212); at 92 there's 36-reg headroom to
// the 128 cliff and 4 waves/SIMD is grid-capped anyway.
// Changes:
//  1. L7 on ALL 4 waves: wave w owns nodes [32w,+32), lane n/n+32 split
//     rows 0-7/8-15 (r25-proven 2-addr A-reads). 2x wave parallelism.
//  2. L6 on 2 waves as its own phase (same split), + __syncthreads.
//  3. Tail (6 levels, cnt2=32..1) UNFENCED: both row-halves' loads
//     pipeline. nu re-association unchanged (bit-exact).
// Tripwires: VGPR>128 or WRITE_SIZE>>4KB => re-fence. absmax must stay 0.
// Structure: 1024 independent blocks, one (t,g) each, no workspace/atomics.

#define C_DIM 16
#define M_DIM 64
#define G_DIM 16
#define T_TREES 64
#define N1 2047
#define NBLOCKS (T_TREES * G_DIM)   // 1024
#define BTS 20                      // padded row stride (floats) for xv-tables

__device__ __forceinline__ float4 f4add(float4 a, float4 b) {
    return make_float4(a.x + b.x, a.y + b.y, a.z + b.z, a.w + b.w);
}
__device__ __forceinline__ float4 f4mul(float4 a, float4 b) {
    return make_float4(a.x * b.x, a.y * b.y, a.z * b.z, a.w * b.w);
}
__device__ __forceinline__ float4 f4fma(float4 a, float4 b, float4 c) {
    return make_float4(fmaf(a.x, b.x, c.x), fmaf(a.y, b.y, c.y),
                       fmaf(a.z, b.z, c.z), fmaf(a.w, b.w, c.w));
}
__device__ __forceinline__ float hsum4(float4 a) { return a.x + a.y + a.z + a.w; }

// Full 16x16 matvec (leaf L8 only): fenced halves (r19-proven liveness cap).
__device__ __forceinline__ float matvec_bt(const float* __restrict__ A,
                                           const float* __restrict__ bt,
                                           const float4 sv[4], float4 bp[4])
{
    float nu = 0.f;
    #pragma unroll
    for (int h = 0; h < 2; ++h) {
        #pragma unroll
        for (int q = 2 * h; q < 2 * h + 2; ++q) {
            const float4 b4 = *(const float4*)(bt + 4 * q);
            float tr[4];
            #pragma unroll
            for (int r = 0; r < 4; ++r) {
                const float4* ar = (const float4*)(A + (4 * q + r) * 16);
                float4 m = f4mul(ar[0], sv[0]);
                m = f4fma(ar[1], sv[1], m);
                m = f4fma(ar[2], sv[2], m);
                m = f4fma(ar[3], sv[3], m);
                tr[r] = hsum4(m);
            }
            bp[q] = f4mul(make_float4(tr[0], tr[1], tr[2], tr[3]), b4);
            nu += hsum4(bp[q]);
        }
        __builtin_amdgcn_sched_barrier(0);   // liveness fence: half-matvec
    }
    return nu;
}

// Half-matvec for the hi/lo split phases: rows r0..r0+7, UNFENCED.
// Outputs bpA (rows r0..r0+3), bpB (rows r0+4..r0+7) and their hsums.
__device__ __forceinline__ void halfmv(const float* __restrict__ A,
                                       const float* __restrict__ bt,
                                       const float4 sv[4], const int r0,
                                       float4& bpA, float4& bpB,
                                       float& hA, float& hB)
{
    float trA[4], trB[4];
    #pragma unroll
    for (int r = 0; r < 4; ++r) {
        const float4* ar = (const float4*)(A + (r0 + r) * 16);
        float4 m = f4mul(ar[0], sv[0]);
        m = f4fma(ar[1], sv[1], m);
        m = f4fma(ar[2], sv[2], m);
        m = f4fma(ar[3], sv[3], m);
        trA[r] = hsum4(m);
    }
    #pragma unroll
    for (int r = 0; r < 4; ++r) {
        const float4* ar = (const float4*)(A + (r0 + 4 + r) * 16);
        float4 m = f4mul(ar[0], sv[0]);
        m = f4fma(ar[1], sv[1], m);
        m = f4fma(ar[2], sv[2], m);
        m = f4fma(ar[3], sv[3], m);
        trB[r] = hsum4(m);
    }
    bpA = f4mul(make_float4(trA[0], trA[1], trA[2], trA[3]),
                *(const float4*)(bt + r0));
    bpB = f4mul(make_float4(trB[0], trB[1], trB[2], trB[3]),
                *(const float4*)(bt + r0 + 4));
    hA = hsum4(bpA);
    hB = hsum4(bpB);
}

__global__ __launch_bounds__(256, 1) void htmm_fused(
    const int* __restrict__ x,
    const int* __restrict__ inv_map,
    const float* __restrict__ lA,
    const float* __restrict__ lB,
    const float* __restrict__ lPi,
    float* __restrict__ out)
{
    const int bid = blockIdx.x;           // 1024 blocks: g = bid>>6, t = bid&63
    const int tid = threadIdx.x;
    const int g = bid >> 6;
    const int t = bid & (T_TREES - 1);

    // ---- manual LDS layout (r21 diet): 32768 B ----
    __shared__ __align__(16) unsigned char smem[32768];
    float* const sA   = (float*)(smem);            //     0 .. 1024   A row-major
    float* const sBt  = (float*)(smem + 1024);     //  1024 .. 6144   Bt[xv][c] stride 20
    float* const sPB  = (float*)(smem + 6144);     //  6144 .. 11264  tA[x]=A·PB[x] (leaf-phase only)
    float* const sLog = (float*)(smem + 11264);    // 11264 .. 11520  (dead after leaf)
    float* const sPi  = (float*)(smem + 11520);    // 11520 .. 11584  (dead after tables)
    float* const buf1 = (float*)(smem + 6144);     // UNION: live from L7 on (8192B)
    unsigned char* const xs = smem + 14336;        // 14336 .. 16384
    float* const buf0 = (float*)(smem + 16384);    // 16384 .. 32768
    float* const wsum = (float*)(smem + 32752);    // buf0 row15 col252-255 (tail-unused)

    // ---- tree symbols (coalesced; 16 same-tree blocks share L2) ----
    {
        const int base = t * N1;
        for (int i = tid; i < N1; i += 256)
            xs[i] = (unsigned char)x[inv_map[base + i]];
    }
    // ---- A softmax (over i within 16-lane segments) ----
    {
        int j = tid >> 4, i = tid & 15;
        float v = lA[(i * C_DIM + j) * G_DIM + g];
        float mx = v;
        #pragma unroll
        for (int m = 1; m < 16; m <<= 1) mx = fmaxf(mx, __shfl_xor(mx, m, 16));
        float e = __expf(v - mx);
        float s = e;
        #pragma unroll
        for (int m = 1; m < 16; m <<= 1) s += __shfl_xor(s, m, 16);
        sA[i * C_DIM + j] = e / s;
    }
    // ---- B softmax (over m), written TRANSPOSED: sBt[xv*BTS + c] ----
    {
        int c = tid >> 4, l16 = tid & 15;
        float e0 = lB[(c * M_DIM + l16 +  0) * G_DIM + g];
        float e1 = lB[(c * M_DIM + l16 + 16) * G_DIM + g];
        float e2 = lB[(c * M_DIM + l16 + 32) * G_DIM + g];
        float e3 = lB[(c * M_DIM + l16 + 48) * G_DIM + g];
        float mx = fmaxf(fmaxf(e0, e1), fmaxf(e2, e3));
        #pragma unroll
        for (int m = 1; m < 16; m <<= 1) mx = fmaxf(mx, __shfl_xor(mx, m, 16));
        e0 = __expf(e0 - mx); e1 = __expf(e1 - mx);
        e2 = __expf(e2 - mx); e3 = __expf(e3 - mx);
        float s = e0 + e1 + e2 + e3;
        #pragma unroll
        for (int m = 1; m < 16; m <<= 1) s += __shfl_xor(s, m, 16);
        float inv = 1.f / s;
        sBt[(l16 +  0) * BTS + c] = e0 * inv;
        sBt[(l16 + 16) * BTS + c] = e1 * inv;
        sBt[(l16 + 32) * BTS + c] = e2 * inv;
        sBt[(l16 + 48) * BTS + c] = e3 * inv;
    }
    if (tid < C_DIM) {  // Pi softmax
        float v = lPi[tid * G_DIM + g];
        float mx = v;
        #pragma unroll
        for (int m = 1; m < 16; m <<= 1) mx = fmaxf(mx, __shfl_xor(mx, m, 16));
        float e = __expf(v - mx);
        float s = e;
        #pragma unroll
        for (int m = 1; m < 16; m <<= 1) s += __shfl_xor(s, m, 16);
        sPi[tid] = e / s;
    }
    __syncthreads();

    // ---- leaf tables + LINEARITY fold: write tA[x] = A·PB[x] ----
    if (tid < M_DIM) {
        const int xv = tid;
        float pb[16]; float nu = 0.f;
        #pragma unroll
        for (int k = 0; k < 16; ++k) {
            pb[k] = sPi[k] * sBt[xv * BTS + k];
            nu += pb[k];
        }
        const float inv = 0.5f / nu;
        #pragma unroll
        for (int k = 0; k < 16; ++k) pb[k] *= inv;
        sLog[xv] = __logf(nu);
        const float4 pv0 = make_float4(pb[0],  pb[1],  pb[2],  pb[3]);
        const float4 pv1 = make_float4(pb[4],  pb[5],  pb[6],  pb[7]);
        const float4 pv2 = make_float4(pb[8],  pb[9],  pb[10], pb[11]);
        const float4 pv3 = make_float4(pb[12], pb[13], pb[14], pb[15]);
        float ta[16];
        #pragma unroll
        for (int i = 0; i < 16; ++i) {
            const float4* ar = (const float4*)(sA + i * 16);
            float4 m = f4mul(ar[0], pv0);
            m = f4fma(ar[1], pv1, m);
            m = f4fma(ar[2], pv2, m);
            m = f4fma(ar[3], pv3, m);
            ta[i] = hsum4(m);
            if ((i & 3) == 3) __builtin_amdgcn_sched_barrier(0);  // cap in-flight
        }
        #pragma unroll
        for (int q = 0; q < 4; ++q)
            *(float4*)(&sPB[xv * BTS + 4 * q]) =
                make_float4(ta[4*q], ta[4*q+1], ta[4*q+2], ta[4*q+3]);
    }
    __syncthreads();

    float ll = 0.f;

    // ---- fused leaves+L9 (TABLE, interleaved) + L8 matvec (r25 form) ----
    {
        const int idx = tid;
        const int p8  = 255 + idx;
        const int xl0 = xs[4 * p8 + 3], xr0 = xs[4 * p8 + 4];
        const int xl1 = xs[4 * p8 + 5], xr1 = xs[4 * p8 + 6];
        const int xva = xs[2 * p8 + 1], xvb = xs[2 * p8 + 2];
        const int xv8 = xs[p8];

        const float* tl0 = &sPB[xl0 * BTS];
        const float* tr0 = &sPB[xr0 * BTS];
        const float* tl1 = &sPB[xl1 * BTS];
        const float* tr1 = &sPB[xr1 * BTS];
        const float* bta = &sBt[xva * BTS];
        const float* btb = &sBt[xvb * BTS];

        float4 bpa[4], bpb[4];
        float nua = 0.f, nub = 0.f;
        #pragma unroll
        for (int q = 0; q < 4; ++q) {
            float4 tva = f4add(*(const float4*)(tl0 + 4*q),
                               *(const float4*)(tr0 + 4*q));
            float4 tvb = f4add(*(const float4*)(tl1 + 4*q),
                               *(const float4*)(tr1 + 4*q));
            bpa[q] = f4mul(tva, *(const float4*)(bta + 4*q));
            bpb[q] = f4mul(tvb, *(const float4*)(btb + 4*q));
            nua += hsum4(bpa[q]);
            nub += hsum4(bpb[q]);
        }
        const float ia = 0.5f / nua, ib = 0.5f / nub;
        float4 s8v[4];
        #pragma unroll
        for (int q = 0; q < 4; ++q)
            s8v[q] = f4add(f4mul(bpa[q], make_float4(ia, ia, ia, ia)),
                           f4mul(bpb[q], make_float4(ib, ib, ib, ib)));

        float4 bp[4];
        const float nu8 = matvec_bt(sA, &sBt[xv8 * BTS], s8v, bp);
        ll += sLog[xl0] + sLog[xr0] + sLog[xl1] + sLog[xr1]
            + __logf(nua * nub * nu8);
        const float inv = 1.f / nu8;
        #pragma unroll
        for (int q = 0; q < 4; ++q) {
            buf0[(4*q + 0) * 256 + idx] = bp[q].x * inv;
            buf0[(4*q + 1) * 256 + idx] = bp[q].y * inv;
            buf0[(4*q + 2) * 256 + idx] = bp[q].z * inv;
            buf0[(4*q + 3) * 256 + idx] = bp[q].w * inv;
        }
    }
    __syncthreads();

    // ---- L7: 128 nodes on ALL 4 waves, hi/lo split (unfenced) ----
    {
        const int w    = tid >> 6;            // wave 0..3
        const int half = (tid >> 5) & 1;      // 0: rows 0-7, 1: rows 8-15
        const int n    = 32 * w + (tid & 31); // node 0..127
        float4 sv[4];
        #pragma unroll
        for (int q = 0; q < 4; ++q) {
            float2 c0 = *(const float2*)(&buf0[(4*q + 0) * 256 + 2 * n]);
            float2 c1 = *(const float2*)(&buf0[(4*q + 1) * 256 + 2 * n]);
            float2 c2 = *(const float2*)(&buf0[(4*q + 2) * 256 + 2 * n]);
            float2 c3 = *(const float2*)(&buf0[(4*q + 3) * 256 + 2 * n]);
            sv[q] = make_float4(0.5f * (c0.x + c0.y), 0.5f * (c1.x + c1.y),
                                0.5f * (c2.x + c2.y), 0.5f * (c3.x + c3.y));
        }
        const int xv = xs[127 + n];
        const int r0 = half * 8;
        float4 bpA, bpB; float hA, hB;
        halfmv(sA, &sBt[xv * BTS], sv, r0, bpA, bpB, hA, hB);
        const float pA = __shfl_xor(hA, 32, 64);
        const float pB = __shfl_xor(hB, 32, 64);
        const float nu = half ? (((pA + pB) + hA) + hB)
                              : (((hA + hB) + pA) + pB);
        if (half == 0) ll += __logf(nu);
        const float inv = 1.f / nu;
        buf1[(r0 + 0) * 128 + n] = bpA.x * inv;
        buf1[(r0 + 1) * 128 + n] = bpA.y * inv;
        buf1[(r0 + 2) * 128 + n] = bpA.z * inv;
        buf1[(r0 + 3) * 128 + n] = bpA.w * inv;
        buf1[(r0 + 4) * 128 + n] = bpB.x * inv;
        buf1[(r0 + 5) * 128 + n] = bpB.y * inv;
        buf1[(r0 + 6) * 128 + n] = bpB.z * inv;
        buf1[(r0 + 7) * 128 + n] = bpB.w * inv;
    }
    __syncthreads();

    // ---- L6: 64 nodes on 2 waves, hi/lo split (unfenced) ----
    if (tid < 128) {
        const int w    = tid >> 6;            // wave 0..1
        const int half = (tid >> 5) & 1;
        const int n    = 32 * w + (tid & 31); // node 0..63
        float4 sv[4];
        #pragma unroll
        for (int q = 0; q < 4; ++q) {
            float2 c0 = *(const float2*)(&buf1[(4*q + 0) * 128 + 2 * n]);
            float2 c1 = *(const float2*)(&buf1[(4*q + 1) * 128 + 2 * n]);
            float2 c2 = *(const float2*)(&buf1[(4*q + 2) * 128 + 2 * n]);
            float2 c3 = *(const float2*)(&buf1[(4*q + 3) * 128 + 2 * n]);
            sv[q] = make_float4(0.5f * (c0.x + c0.y), 0.5f * (c1.x + c1.y),
                                0.5f * (c2.x + c2.y), 0.5f * (c3.x + c3.y));
        }
        const int xv = xs[63 + n];
        const int r0 = half * 8;
        float4 bpA, bpB; float hA, hB;
        halfmv(sA, &sBt[xv * BTS], sv, r0, bpA, bpB, hA, hB);
        const float pA = __shfl_xor(hA, 32, 64);
        const float pB = __shfl_xor(hB, 32, 64);
        const float nu = half ? (((pA + pB) + hA) + hB)
                              : (((hA + hB) + pA) + pB);
        if (half == 0) ll += __logf(nu);
        const float inv = 1.f / nu;
        buf0[(r0 + 0) * 256 + n] = bpA.x * inv;
        buf0[(r0 + 1) * 256 + n] = bpA.y * inv;
        buf0[(r0 + 2) * 256 + n] = bpA.z * inv;
        buf0[(r0 + 3) * 256 + n] = bpA.w * inv;
        buf0[(r0 + 4) * 256 + n] = bpB.x * inv;
        buf0[(r0 + 5) * 256 + n] = bpB.y * inv;
        buf0[(r0 + 6) * 256 + n] = bpB.z * inv;
        buf0[(r0 + 7) * 256 + n] = bpB.w * inv;
    }
    __syncthreads();

    // ---- tail L5..L0 (cnt2=32..1): wave 0, hi/lo split, UNFENCED ----
    if (tid < 64) {
        float* cur = buf0; int cs = 256;
        float* nxt = buf1; int ns = 128;
        for (int cnt2 = 32; cnt2 >= 1; cnt2 >>= 1) {
            const int half = tid >> 5;
            const int n    = tid & 31;
            if (n < cnt2) {
                float4 sv[4];
                #pragma unroll
                for (int q = 0; q < 4; ++q) {
                    float2 c0 = *(const float2*)(&cur[(4*q + 0) * cs + 2 * n]);
                    float2 c1 = *(const float2*)(&cur[(4*q + 1) * cs + 2 * n]);
                    float2 c2 = *(const float2*)(&cur[(4*q + 2) * cs + 2 * n]);
                    float2 c3 = *(const float2*)(&cur[(4*q + 3) * cs + 2 * n]);
                    sv[q] = make_float4(0.5f * (c0.x + c0.y), 0.5f * (c1.x + c1.y),
                                        0.5f * (c2.x + c2.y), 0.5f * (c3.x + c3.y));
                }
                const int xv = xs[cnt2 - 1 + n];
                const int r0 = half * 8;
                float4 bpA, bpB; float hA, hB;
                halfmv(sA, &sBt[xv * BTS], sv, r0, bpA, bpB, hA, hB);
                const float pA = __shfl_xor(hA, 32, 64);
                const float pB = __shfl_xor(hB, 32, 64);
                const float nu = half ? (((pA + pB) + hA) + hB)
                                      : (((hA + hB) + pA) + pB);
                if (half == 0) ll += __logf(nu);
                const float inv = 1.f / nu;
                nxt[(r0 + 0) * ns + n] = bpA.x * inv;
                nxt[(r0 + 1) * ns + n] = bpA.y * inv;
                nxt[(r0 + 2) * ns + n] = bpA.z * inv;
                nxt[(r0 + 3) * ns + n] = bpA.w * inv;
                nxt[(r0 + 4) * ns + n] = bpB.x * inv;
                nxt[(r0 + 5) * ns + n] = bpB.y * inv;
                nxt[(r0 + 6) * ns + n] = bpB.z * inv;
                nxt[(r0 + 7) * ns + n] = bpB.w * inv;
            }
            asm volatile("s_waitcnt lgkmcnt(0)" ::: "memory");
            __builtin_amdgcn_wave_barrier();
            float* tp = cur; cur = nxt; nxt = tp;
            int ts = cs; cs = ns; ns = ts;
        }
    }

    // ---- reduce ll across block (wsum in buf0 row15 cols252-255) ----
    float v = ll;
    #pragma unroll
    for (int off = 32; off > 0; off >>= 1) v += __shfl_down(v, off, 64);
    if ((tid & 63) == 0) wsum[tid >> 6] = v;
    __syncthreads();
    if (tid == 0) out[t * G_DIM + g] = wsum[0] + wsum[1] + wsum[2] + wsum[3];
}

extern "C" void kernel_launch(void* const* d_in, const int* in_sizes, int n_in,
                              void* d_out, int out_size, void* d_ws, size_t ws_size,
                              hipStream_t stream) {
    const int*   x       = (const int*)d_in[0];
    const int*   inv_map = (const int*)d_in[6];
    const float* lA      = (const float*)d_in[7];
    const float* lB      = (const float*)d_in[8];
    const float* lPi     = (const float*)d_in[9];
    float* out = (float*)d_out;

    htmm_fused<<<dim3(NBLOCKS), dim3(256), 0, stream>>>(
        x, inv_map, lA, lB, lPi, out);
}

// Round 18
// 94.675 us; speedup vs baseline: 2.1044x; 1.0051x over previous
//
#include <hip/hip_runtime.h>

// UniformBottomUpHTMM: T=64 trees, depth 10 (N1=2047 heap), C=16, M=64,
// G=16. r29: de-serialize the last two fenced phases.
// r28 (L7 4-wave + L6 2-wave hi/lo split, unfenced tail) dropped the
// kernel out of rocprof's top-5 (<39us; ~30us from bench totals). VGPR 92
// with 36-reg headroom to the 128 cliff; 4 blocks/CU is grid-capped so
// VGPR<=128 is free.
// Changes:
//  1. matvec_bt (leaf L8) UNFENCED: compiler may pipeline all 16 A-row
//     loads (<=64 regs in flight; est total ~120 < 128).
//  2. Table phase on 2 WAVES with hi/lo row split, unfenced: wave w owns
//     symbols [32w,+32), lane n/n+32 computes rows 0-7/8-15 of tA[xv].
//     pb/nu computed identically per-lane (bit-exact); sLog written once.
//     Halves the per-stream chain of the phase that blocks all 4 waves.
// Tripwires: VGPR>128 or WRITE_SIZE>>4KB => re-fence. absmax must stay 0.
// Structure: 1024 independent blocks, one (t,g) each, no workspace/atomics.

#define C_DIM 16
#define M_DIM 64
#define G_DIM 16
#define T_TREES 64
#define N1 2047
#define NBLOCKS (T_TREES * G_DIM)   // 1024
#define BTS 20                      // padded row stride (floats) for xv-tables

__device__ __forceinline__ float4 f4add(float4 a, float4 b) {
    return make_float4(a.x + b.x, a.y + b.y, a.z + b.z, a.w + b.w);
}
__device__ __forceinline__ float4 f4mul(float4 a, float4 b) {
    return make_float4(a.x * b.x, a.y * b.y, a.z * b.z, a.w * b.w);
}
__device__ __forceinline__ float4 f4fma(float4 a, float4 b, float4 c) {
    return make_float4(fmaf(a.x, b.x, c.x), fmaf(a.y, b.y, c.y),
                       fmaf(a.z, b.z, c.z), fmaf(a.w, b.w, c.w));
}
__device__ __forceinline__ float hsum4(float4 a) { return a.x + a.y + a.z + a.w; }

// Full 16x16 matvec (leaf L8 only): UNFENCED (r29) -- loads may pipeline.
__device__ __forceinline__ float matvec_bt(const float* __restrict__ A,
                                           const float* __restrict__ bt,
                                           const float4 sv[4], float4 bp[4])
{
    float nu = 0.f;
    #pragma unroll
    for (int q = 0; q < 4; ++q) {
        const float4 b4 = *(const float4*)(bt + 4 * q);
        float tr[4];
        #pragma unroll
        for (int r = 0; r < 4; ++r) {
            const float4* ar = (const float4*)(A + (4 * q + r) * 16);
            float4 m = f4mul(ar[0], sv[0]);
            m = f4fma(ar[1], sv[1], m);
            m = f4fma(ar[2], sv[2], m);
            m = f4fma(ar[3], sv[3], m);
            tr[r] = hsum4(m);
        }
        bp[q] = f4mul(make_float4(tr[0], tr[1], tr[2], tr[3]), b4);
        nu += hsum4(bp[q]);
    }
    return nu;
}

// Half-matvec for the hi/lo split phases: rows r0..r0+7, UNFENCED.
__device__ __forceinline__ void halfmv(const float* __restrict__ A,
                                       const float* __restrict__ bt,
                                       const float4 sv[4], const int r0,
                                       float4& bpA, float4& bpB,
                                       float& hA, float& hB)
{
    float trA[4], trB[4];
    #pragma unroll
    for (int r = 0; r < 4; ++r) {
        const float4* ar = (const float4*)(A + (r0 + r) * 16);
        float4 m = f4mul(ar[0], sv[0]);
        m = f4fma(ar[1], sv[1], m);
        m = f4fma(ar[2], sv[2], m);
        m = f4fma(ar[3], sv[3], m);
        trA[r] = hsum4(m);
    }
    #pragma unroll
    for (int r = 0; r < 4; ++r) {
        const float4* ar = (const float4*)(A + (r0 + 4 + r) * 16);
        float4 m = f4mul(ar[0], sv[0]);
        m = f4fma(ar[1], sv[1], m);
        m = f4fma(ar[2], sv[2], m);
        m = f4fma(ar[3], sv[3], m);
        trB[r] = hsum4(m);
    }
    bpA = f4mul(make_float4(trA[0], trA[1], trA[2], trA[3]),
                *(const float4*)(bt + r0));
    bpB = f4mul(make_float4(trB[0], trB[1], trB[2], trB[3]),
                *(const float4*)(bt + r0 + 4));
    hA = hsum4(bpA);
    hB = hsum4(bpB);
}

__global__ __launch_bounds__(256, 1) void htmm_fused(
    const int* __restrict__ x,
    const int* __restrict__ inv_map,
    const float* __restrict__ lA,
    const float* __restrict__ lB,
    const float* __restrict__ lPi,
    float* __restrict__ out)
{
    const int bid = blockIdx.x;           // 1024 blocks: g = bid>>6, t = bid&63
    const int tid = threadIdx.x;
    const int g = bid >> 6;
    const int t = bid & (T_TREES - 1);

    // ---- manual LDS layout (r21 diet): 32768 B ----
    __shared__ __align__(16) unsigned char smem[32768];
    float* const sA   = (float*)(smem);            //     0 .. 1024   A row-major
    float* const sBt  = (float*)(smem + 1024);     //  1024 .. 6144   Bt[xv][c] stride 20
    float* const sPB  = (float*)(smem + 6144);     //  6144 .. 11264  tA[x]=A·PB[x] (leaf-phase only)
    float* const sLog = (float*)(smem + 11264);    // 11264 .. 11520  (dead after leaf)
    float* const sPi  = (float*)(smem + 11520);    // 11520 .. 11584  (dead after tables)
    float* const buf1 = (float*)(smem + 6144);     // UNION: live from L7 on (8192B)
    unsigned char* const xs = smem + 14336;        // 14336 .. 16384
    float* const buf0 = (float*)(smem + 16384);    // 16384 .. 32768
    float* const wsum = (float*)(smem + 32752);    // buf0 row15 col252-255 (tail-unused)

    // ---- tree symbols (coalesced; 16 same-tree blocks share L2) ----
    {
        const int base = t * N1;
        for (int i = tid; i < N1; i += 256)
            xs[i] = (unsigned char)x[inv_map[base + i]];
    }
    // ---- A softmax (over i within 16-lane segments) ----
    {
        int j = tid >> 4, i = tid & 15;
        float v = lA[(i * C_DIM + j) * G_DIM + g];
        float mx = v;
        #pragma unroll
        for (int m = 1; m < 16; m <<= 1) mx = fmaxf(mx, __shfl_xor(mx, m, 16));
        float e = __expf(v - mx);
        float s = e;
        #pragma unroll
        for (int m = 1; m < 16; m <<= 1) s += __shfl_xor(s, m, 16);
        sA[i * C_DIM + j] = e / s;
    }
    // ---- B softmax (over m), written TRANSPOSED: sBt[xv*BTS + c] ----
    {
        int c = tid >> 4, l16 = tid & 15;
        float e0 = lB[(c * M_DIM + l16 +  0) * G_DIM + g];
        float e1 = lB[(c * M_DIM + l16 + 16) * G_DIM + g];
        float e2 = lB[(c * M_DIM + l16 + 32) * G_DIM + g];
        float e3 = lB[(c * M_DIM + l16 + 48) * G_DIM + g];
        float mx = fmaxf(fmaxf(e0, e1), fmaxf(e2, e3));
        #pragma unroll
        for (int m = 1; m < 16; m <<= 1) mx = fmaxf(mx, __shfl_xor(mx, m, 16));
        e0 = __expf(e0 - mx); e1 = __expf(e1 - mx);
        e2 = __expf(e2 - mx); e3 = __expf(e3 - mx);
        float s = e0 + e1 + e2 + e3;
        #pragma unroll
        for (int m = 1; m < 16; m <<= 1) s += __shfl_xor(s, m, 16);
        float inv = 1.f / s;
        sBt[(l16 +  0) * BTS + c] = e0 * inv;
        sBt[(l16 + 16) * BTS + c] = e1 * inv;
        sBt[(l16 + 32) * BTS + c] = e2 * inv;
        sBt[(l16 + 48) * BTS + c] = e3 * inv;
    }
    if (tid < C_DIM) {  // Pi softmax
        float v = lPi[tid * G_DIM + g];
        float mx = v;
        #pragma unroll
        for (int m = 1; m < 16; m <<= 1) mx = fmaxf(mx, __shfl_xor(mx, m, 16));
        float e = __expf(v - mx);
        float s = e;
        #pragma unroll
        for (int m = 1; m < 16; m <<= 1) s += __shfl_xor(s, m, 16);
        sPi[tid] = e / s;
    }
    __syncthreads();

    // ---- leaf tables + LINEARITY fold on 2 WAVES, hi/lo split ----
    // Wave w owns symbols [32w,32w+32); lane n / n+32 computes rows
    // 0-7 / 8-15 of tA[xv]=A·PB[xv]. pb/nu identical per-lane (bit-exact).
    if (tid < 128) {
        const int w    = tid >> 6;            // wave 0..1
        const int half = (tid >> 5) & 1;      // 0: rows 0-7, 1: rows 8-15
        const int xv   = 32 * w + (tid & 31); // symbol 0..63
        float pb[16]; float nu = 0.f;
        #pragma unroll
        for (int k = 0; k < 16; ++k) {
            pb[k] = sPi[k] * sBt[xv * BTS + k];
            nu += pb[k];
        }
        const float inv = 0.5f / nu;
        #pragma unroll
        for (int k = 0; k < 16; ++k) pb[k] *= inv;
        if (half == 0) sLog[xv] = __logf(nu);
        const float4 pv0 = make_float4(pb[0],  pb[1],  pb[2],  pb[3]);
        const float4 pv1 = make_float4(pb[4],  pb[5],  pb[6],  pb[7]);
        const float4 pv2 = make_float4(pb[8],  pb[9],  pb[10], pb[11]);
        const float4 pv3 = make_float4(pb[12], pb[13], pb[14], pb[15]);
        const int r0 = half * 8;
        float ta[8];
        #pragma unroll
        for (int i = 0; i < 8; ++i) {
            const float4* ar = (const float4*)(sA + (r0 + i) * 16);
            float4 m = f4mul(ar[0], pv0);
            m = f4fma(ar[1], pv1, m);
            m = f4fma(ar[2], pv2, m);
            m = f4fma(ar[3], pv3, m);
            ta[i] = hsum4(m);
        }
        *(float4*)(&sPB[xv * BTS + r0])     = make_float4(ta[0], ta[1], ta[2], ta[3]);
        *(float4*)(&sPB[xv * BTS + r0 + 4]) = make_float4(ta[4], ta[5], ta[6], ta[7]);
    }
    __syncthreads();

    float ll = 0.f;

    // ---- fused leaves+L9 (TABLE, interleaved) + L8 matvec ----
    {
        const int idx = tid;
        const int p8  = 255 + idx;
        const int xl0 = xs[4 * p8 + 3], xr0 = xs[4 * p8 + 4];
        const int xl1 = xs[4 * p8 + 5], xr1 = xs[4 * p8 + 6];
        const int xva = xs[2 * p8 + 1], xvb = xs[2 * p8 + 2];
        const int xv8 = xs[p8];

        const float* tl0 = &sPB[xl0 * BTS];
        const float* tr0 = &sPB[xr0 * BTS];
        const float* tl1 = &sPB[xl1 * BTS];
        const float* tr1 = &sPB[xr1 * BTS];
        const float* bta = &sBt[xva * BTS];
        const float* btb = &sBt[xvb * BTS];

        float4 bpa[4], bpb[4];
        float nua = 0.f, nub = 0.f;
        #pragma unroll
        for (int q = 0; q < 4; ++q) {
            float4 tva = f4add(*(const float4*)(tl0 + 4*q),
                               *(const float4*)(tr0 + 4*q));
            float4 tvb = f4add(*(const float4*)(tl1 + 4*q),
                               *(const float4*)(tr1 + 4*q));
            bpa[q] = f4mul(tva, *(const float4*)(bta + 4*q));
            bpb[q] = f4mul(tvb, *(const float4*)(btb + 4*q));
            nua += hsum4(bpa[q]);
            nub += hsum4(bpb[q]);
        }
        const float ia = 0.5f / nua, ib = 0.5f / nub;
        float4 s8v[4];
        #pragma unroll
        for (int q = 0; q < 4; ++q)
            s8v[q] = f4add(f4mul(bpa[q], make_float4(ia, ia, ia, ia)),
                           f4mul(bpb[q], make_float4(ib, ib, ib, ib)));

        float4 bp[4];
        const float nu8 = matvec_bt(sA, &sBt[xv8 * BTS], s8v, bp);
        ll += sLog[xl0] + sLog[xr0] + sLog[xl1] + sLog[xr1]
            + __logf(nua * nub * nu8);
        const float inv = 1.f / nu8;
        #pragma unroll
        for (int q = 0; q < 4; ++q) {
            buf0[(4*q + 0) * 256 + idx] = bp[q].x * inv;
            buf0[(4*q + 1) * 256 + idx] = bp[q].y * inv;
            buf0[(4*q + 2) * 256 + idx] = bp[q].z * inv;
            buf0[(4*q + 3) * 256 + idx] = bp[q].w * inv;
        }
    }
    __syncthreads();

    // ---- L7: 128 nodes on ALL 4 waves, hi/lo split (unfenced) ----
    {
        const int w    = tid >> 6;            // wave 0..3
        const int half = (tid >> 5) & 1;      // 0: rows 0-7, 1: rows 8-15
        const int n    = 32 * w + (tid & 31); // node 0..127
        float4 sv[4];
        #pragma unroll
        for (int q = 0; q < 4; ++q) {
            float2 c0 = *(const float2*)(&buf0[(4*q + 0) * 256 + 2 * n]);
            float2 c1 = *(const float2*)(&buf0[(4*q + 1) * 256 + 2 * n]);
            float2 c2 = *(const float2*)(&buf0[(4*q + 2) * 256 + 2 * n]);
            float2 c3 = *(const float2*)(&buf0[(4*q + 3) * 256 + 2 * n]);
            sv[q] = make_float4(0.5f * (c0.x + c0.y), 0.5f * (c1.x + c1.y),
                                0.5f * (c2.x + c2.y), 0.5f * (c3.x + c3.y));
        }
        const int xv = xs[127 + n];
        const int r0 = half * 8;
        float4 bpA, bpB; float hA, hB;
        halfmv(sA, &sBt[xv * BTS], sv, r0, bpA, bpB, hA, hB);
        const float pA = __shfl_xor(hA, 32, 64);
        const float pB = __shfl_xor(hB, 32, 64);
        const float nu = half ? (((pA + pB) + hA) + hB)
                              : (((hA + hB) + pA) + pB);
        if (half == 0) ll += __logf(nu);
        const float inv = 1.f / nu;
        buf1[(r0 + 0) * 128 + n] = bpA.x * inv;
        buf1[(r0 + 1) * 128 + n] = bpA.y * inv;
        buf1[(r0 + 2) * 128 + n] = bpA.z * inv;
        buf1[(r0 + 3) * 128 + n] = bpA.w * inv;
        buf1[(r0 + 4) * 128 + n] = bpB.x * inv;
        buf1[(r0 + 5) * 128 + n] = bpB.y * inv;
        buf1[(r0 + 6) * 128 + n] = bpB.z * inv;
        buf1[(r0 + 7) * 128 + n] = bpB.w * inv;
    }
    __syncthreads();

    // ---- L6: 64 nodes on 2 waves, hi/lo split (unfenced) ----
    if (tid < 128) {
        const int w    = tid >> 6;            // wave 0..1
        const int half = (tid >> 5) & 1;
        const int n    = 32 * w + (tid & 31); // node 0..63
        float4 sv[4];
        #pragma unroll
        for (int q = 0; q < 4; ++q) {
            float2 c0 = *(const float2*)(&buf1[(4*q + 0) * 128 + 2 * n]);
            float2 c1 = *(const float2*)(&buf1[(4*q + 1) * 128 + 2 * n]);
            float2 c2 = *(const float2*)(&buf1[(4*q + 2) * 128 + 2 * n]);
            float2 c3 = *(const float2*)(&buf1[(4*q + 3) * 128 + 2 * n]);
            sv[q] = make_float4(0.5f * (c0.x + c0.y), 0.5f * (c1.x + c1.y),
                                0.5f * (c2.x + c2.y), 0.5f * (c3.x + c3.y));
        }
        const int xv = xs[63 + n];
        const int r0 = half * 8;
        float4 bpA, bpB; float hA, hB;
        halfmv(sA, &sBt[xv * BTS], sv, r0, bpA, bpB, hA, hB);
        const float pA = __shfl_xor(hA, 32, 64);
        const float pB = __shfl_xor(hB, 32, 64);
        const float nu = half ? (((pA + pB) + hA) + hB)
                              : (((hA + hB) + pA) + pB);
        if (half == 0) ll += __logf(nu);
        const float inv = 1.f / nu;
        buf0[(r0 + 0) * 256 + n] = bpA.x * inv;
        buf0[(r0 + 1) * 256 + n] = bpA.y * inv;
        buf0[(r0 + 2) * 256 + n] = bpA.z * inv;
        buf0[(r0 + 3) * 256 + n] = bpA.w * inv;
        buf0[(r0 + 4) * 256 + n] = bpB.x * inv;
        buf0[(r0 + 5) * 256 + n] = bpB.y * inv;
        buf0[(r0 + 6) * 256 + n] = bpB.z * inv;
        buf0[(r0 + 7) * 256 + n] = bpB.w * inv;
    }
    __syncthreads();

    // ---- tail L5..L0 (cnt2=32..1): wave 0, hi/lo split, unfenced ----
    if (tid < 64) {
        float* cur = buf0; int cs = 256;
        float* nxt = buf1; int ns = 128;
        for (int cnt2 = 32; cnt2 >= 1; cnt2 >>= 1) {
            const int half = tid >> 5;
            const int n    = tid & 31;
            if (n < cnt2) {
                float4 sv[4];
                #pragma unroll
                for (int q = 0; q < 4; ++q) {
                    float2 c0 = *(const float2*)(&cur[(4*q + 0) * cs + 2 * n]);
                    float2 c1 = *(const float2*)(&cur[(4*q + 1) * cs + 2 * n]);
                    float2 c2 = *(const float2*)(&cur[(4*q + 2) * cs + 2 * n]);
                    float2 c3 = *(const float2*)(&cur[(4*q + 3) * cs + 2 * n]);
                    sv[q] = make_float4(0.5f * (c0.x + c0.y), 0.5f * (c1.x + c1.y),
                                        0.5f * (c2.x + c2.y), 0.5f * (c3.x + c3.y));
                }
                const int xv = xs[cnt2 - 1 + n];
                const int r0 = half * 8;
                float4 bpA, bpB; float hA, hB;
                halfmv(sA, &sBt[xv * BTS], sv, r0, bpA, bpB, hA, hB);
                const float pA = __shfl_xor(hA, 32, 64);
                const float pB = __shfl_xor(hB, 32, 64);
                const float nu = half ? (((pA + pB) + hA) + hB)
                                      : (((hA + hB) + pA) + pB);
                if (half == 0) ll += __logf(nu);
                const float inv = 1.f / nu;
                nxt[(r0 + 0) * ns + n] = bpA.x * inv;
                nxt[(r0 + 1) * ns + n] = bpA.y * inv;
                nxt[(r0 + 2) * ns + n] = bpA.z * inv;
                nxt[(r0 + 3) * ns + n] = bpA.w * inv;
                nxt[(r0 + 4) * ns + n] = bpB.x * inv;
                nxt[(r0 + 5) * ns + n] = bpB.y * inv;
                nxt[(r0 + 6) * ns + n] = bpB.z * inv;
                nxt[(r0 + 7) * ns + n] = bpB.w * inv;
            }
            asm volatile("s_waitcnt lgkmcnt(0)" ::: "memory");
            __builtin_amdgcn_wave_barrier();
            float* tp = cur; cur = nxt; nxt = tp;
            int ts = cs; cs = ns; ns = ts;
        }
    }

    // ---- reduce ll across block (wsum in buf0 row15 cols252-255) ----
    float v = ll;
    #pragma unroll
    for (int off = 32; off > 0; off >>= 1) v += __shfl_down(v, off, 64);
    if ((tid & 63) == 0) wsum[tid >> 6] = v;
    __syncthreads();
    if (tid == 0) out[t * G_DIM + g] = wsum[0] + wsum[1] + wsum[2] + wsum[3];
}

extern "C" void kernel_launch(void* const* d_in, const int* in_sizes, int n_in,
                              void* d_out, int out_size, void* d_ws, size_t ws_size,
                              hipStream_t stream) {
    const int*   x       = (const int*)d_in[0];
    const int*   inv_map = (const int*)d_in[6];
    const float* lA      = (const float*)d_in[7];
    const float* lB      = (const float*)d_in[8];
    const float* lPi     = (const float*)d_in[9];
    float* out = (float*)d_out;

    htmm_fused<<<dim3(NBLOCKS), dim3(256), 0, stream>>>(
        x, inv_map, lA, lB, lPi, out);
}